// Round 15
// baseline (289.537 us; speedup 1.0000x reference)
//
#include <hip/hip_runtime.h>
#include <hip/hip_cooperative_groups.h>
#include <math.h>

namespace cg = cooperative_groups;

#define N_NODES 100000
#define N_EDGES 3200000
#define N_GRAPHS 64
#define BW 512                               // nodes per bucket
#define LSH 9
#define LMASK 511u
#define NBUCK ((N_NODES + BW - 1) / BW)      // 196
#define CHUNK_E 16384
#define NCHUNK ((N_EDGES + CHUNK_E - 1) / CHUNK_E)  // 196 == NBUCK (one grid, two roles)
#define CAP_E 18432                          // per-bucket capacity (mean 16384, +16 sigma)
#define POOL_SCALE 1024.0f
#define POOL_INV (1.0f / 1024.0f)
#define SENT ((unsigned int)N_NODES << LSH)  // sentinel edge -> ac[N_NODES] == (0,0)

// ---- fused build (cooperative): phase D (chunk scatter) -> grid.sync ->
// phase E1 (bucket hist/scan -> rowstart/dinv/s) -> grid.sync (s visibility)
// -> phase E2 (sort scatter + fused layer-1 fsum -> ac).
// Same 196x1024 grid for all phases; replaces k_part/k_sorta/k_sortb and their
// launch gaps + gcur/rowstart/dinv round-trips. Bucket-confined writes keep the
// active write set at ~196 moving pointers — rounds 2/10: per-NODE cursors /
// random global atomics thrash the coherence point (100-200MB WRITE).
__global__ __launch_bounds__(1024, 1)
void k_build(const int* __restrict__ src, const int* __restrict__ dst,
             unsigned int* __restrict__ gcur, unsigned int* __restrict__ packed,
             unsigned int* __restrict__ packed2, unsigned int* __restrict__ rowstart,
             const float* __restrict__ x, float* __restrict__ dinv, float* __restrict__ s,
             float2* __restrict__ ac) {
    __shared__ unsigned int h1[NBUCK];       // phase D hist / scatter cursor
    __shared__ unsigned int sstart[NBUCK];
    __shared__ unsigned int hist[BW];        // phase E node hist
    __shared__ unsigned int scan[BW];        // also reused for the 196-bucket prefix
    __shared__ unsigned int cur[BW];         // absolute scatter cursors
    __shared__ float fsum[BW];
    __shared__ unsigned int swbase;
    cg::grid_group grid = cg::this_grid();
    const int b = blockIdx.x;
    const int t = threadIdx.x;

    // ---- phase D: chunk b -> padded bucket regions (self-reserving) ----
    for (int i = t; i < NBUCK; i += 1024) h1[i] = 0u;
    __syncthreads();
    int e0 = b * CHUNK_E;
    int e1 = min(e0 + CHUNK_E, N_EDGES);
    for (int e = e0 + t; e < e1; e += 1024)
        atomicAdd(&h1[dst[e] >> LSH], 1u);
    __syncthreads();
    for (int i = t; i < NBUCK; i += 1024) {
        unsigned int hh = h1[i];
        sstart[i] = hh ? ((unsigned int)i * CAP_E + atomicAdd(&gcur[i], hh)) : 0u;
        h1[i] = 0u;                          // reuse as scatter cursor
    }
    __syncthreads();
    for (int e = e0 + t; e < e1; e += 1024) {
        int d = dst[e];
        int bk = d >> LSH;
        unsigned int pos = sstart[bk] + atomicAdd(&h1[bk], 1u);
        packed[pos] = ((unsigned int)src[e] << LSH) | ((unsigned int)d & LMASK);
    }

    grid.sync();   // all buckets fully placed; gcur[b] == exact bucket size

    // ---- phase E1: bucket b -> rowstart, dinv, s ----
    // redundant 196-entry prefix of gcur -> this bucket's contiguous base
    unsigned int gv = 0u;
    if (t < 256) { gv = (t < NBUCK) ? gcur[t] : 0u; scan[t] = gv; }
    if (t < BW) hist[t] = 0u;
    if (b == 0 && t == 0) ac[N_NODES] = make_float2(0.0f, 0.0f);  // k_l2 sentinel
    __syncthreads();
    for (int o = 1; o < 256; o <<= 1) {
        unsigned int v = 0u;
        if (t < 256 && t >= o) v = scan[t - o];
        __syncthreads();
        if (t < 256 && t >= o) scan[t] += v;
        __syncthreads();
    }
    if (t == b) swbase = scan[t] - gv;
    __syncthreads();
    const unsigned int wbase = swbase;
    const unsigned int r0 = (unsigned int)b * CAP_E;
    const unsigned int r1 = r0 + gcur[b];
    for (unsigned int e = r0 + t; e < r1; e += 1024)
        atomicAdd(&hist[packed[e] & LMASK], 1u);
    __syncthreads();
    if (t < BW) scan[t] = hist[t];
    __syncthreads();
    for (int o = 1; o < BW; o <<= 1) {
        unsigned int v = 0u;
        if (t < BW && t >= o) v = scan[t - o];
        __syncthreads();
        if (t < BW && t >= o) scan[t] += v;
        __syncthreads();
    }
    float di_reg = 0.0f, s_reg = 0.0f;       // thread t owns node b*BW+t (kept in regs)
    if (t < BW) {
        unsigned int deg = hist[t];
        unsigned int rst = wbase + scan[t] - deg;
        rowstart[b * BW + t] = rst;
        cur[t] = rst;                        // absolute scatter cursor
        fsum[t] = 0.0f;
        int n = b * BW + t;
        if (n < N_NODES) {
            di_reg = 1.0f / sqrtf((float)(deg + 1u));  // +1 self-loop
            dinv[n] = di_reg;
            s_reg = x[n] * di_reg;
            s[n] = s_reg;
        }
    }

    grid.sync();   // all s[] visible before cross-bucket gathers

    // ---- phase E2: sort scatter + fused layer-1 fsum -> ac ----
    // fsum order is LDS-atomic-nondeterministic: same class as the edge order
    // (already atomic); the int-quantized pooling absorbs it.
    for (unsigned int e = r0 + t; e < r1; e += 1024) {
        unsigned int p = packed[e];
        unsigned int d = p & LMASK;
        unsigned int pos = atomicAdd(&cur[d], 1u);
        packed2[pos] = p;
        atomicAdd(&fsum[d], s[p >> LSH]);    // ds_add_f32, L2-resident gather
    }
    __syncthreads();
    if (t < BW) {
        int n = b * BW + t;
        if (n < N_NODES)
            ac[n] = make_float2(di_reg, di_reg * di_reg * (fsum[t] + s_reg));
    }
}

// ---- layer 2: one 64-lane wave per node, lane j = column j ----
// ROUND-5 KERNEL VERBATIM — proven 36 VGPR, zero scratch, 53-56 µs, FETCH 10 MB.
// DO NOT EDIT THIS KERNEL'S BODY: rounds 6/7/8 each made small changes (packed
// math; prefetch+4 accumulators; even a 2-accumulator algebra tweak) and ALL
// tipped the register allocator into demoting w2c[32] to scratch — 100-310 MB
// of HBM scratch traffic, 2-3x kernel slowdown, and graph-replay-wide damage.
// The codegen sits exactly on a register-bucket boundary.
#define NPW 8

#define EDGE_PAIR(P) { \
    float4 q_ = Epair4[(P)]; \
    H += fmaxf(fmaf(q_.y, w1j, q_.x * b1j), 0.0f); \
    H += fmaxf(fmaf(q_.w, w1j, q_.z * b1j), 0.0f); }

#define BLOCK16(P0) { \
    EDGE_PAIR((P0) + 0) EDGE_PAIR((P0) + 1) EDGE_PAIR((P0) + 2) EDGE_PAIR((P0) + 3) \
    EDGE_PAIR((P0) + 4) EDGE_PAIR((P0) + 5) EDGE_PAIR((P0) + 6) EDGE_PAIR((P0) + 7) }

__global__ __launch_bounds__(256, 6)
void k_l2(const unsigned int* __restrict__ rowstart, const unsigned int* __restrict__ packed2,
          const float2* __restrict__ ac,
          const float* __restrict__ W1, const float* __restrict__ b1,
          const float* __restrict__ W2, const float* __restrict__ b2,
          const int* __restrict__ batch, int* __restrict__ gsumi) {
    __shared__ float Hrow[4][64];    // one 64-float row per wave; wave-private
    __shared__ float4 Ebuf[4][32];   // 64 (ax,ay) pairs per wave, read as float4 (2 edges/read)
    const int lane = threadIdx.x & 63;
    const int wv   = threadIdx.x >> 6;
    const int k    = lane & 31;     // output column for matvec/pool
    const int jh   = lane >> 5;     // which half of the 64-wide hidden dim this lane reduces
    const int j0   = jh * 32;

    const float w1j = W1[lane];
    const float b1j = b1[lane];
    const float b2k = b2[k];
    float w2c[32];
#pragma unroll
    for (int j = 0; j < 32; j++) w2c[j] = W2[(j0 + j) * 32 + k];

    float4* Epair4 = &Ebuf[wv][0];                 // wave-uniform base
    float2* Ewr    = (float2*)&Ebuf[wv][0];        // per-lane write slot

    int n0 = (blockIdx.x * 4 + wv) * NPW;
    float racc = 0.0f;
    int curg = -1;
    for (int i = 0; i < NPW; i++) {
        int n = n0 + i;
        if (n >= N_NODES) break;
        unsigned int rs = rowstart[n], re = rowstart[n + 1];
        float2 acn = ac[n];
        // self-loop contribution
        float H = fmaxf(fmaf(acn.y, w1j, acn.x * b1j), 0.0f);
        unsigned int e0 = rs;
        // full 64-slot batches (deg >= 64, rare at Poisson(32))
        while (e0 + 64u <= re) {
            unsigned int p = packed2[e0 + lane];     // all lanes valid
            Ewr[lane] = ac[p >> LSH];                // gather -> wave-private LDS (ds_write_b64)
            BLOCK16(0) BLOCK16(8) BLOCK16(16) BLOCK16(24)
            e0 += 64u;
        }
        unsigned int rem = re - e0;                  // 0..63
        if (rem) {
            unsigned int idx = e0 + lane;
            unsigned int p = SENT;                   // sentinel -> ac[N_NODES] == (0,0)
            if (idx < re) p = packed2[idx];          // exec-masked load, no OOB
            Ewr[lane] = ac[p >> LSH];
            switch ((rem + 15u) >> 4) {              // 1..4 blocks of 16 slots (8 pairs)
                case 4: BLOCK16(24); [[fallthrough]];
                case 3: BLOCK16(16); [[fallthrough]];
                case 2: BLOCK16(8);  [[fallthrough]];
                case 1: BLOCK16(0);
            }
        }
        // matvec: out_k = relu(dinv_n * (H . W2[:,k]) + b2[k])
        Hrow[wv][lane] = H;     // same-wave ds ordering: visible to this wave without barrier
        float accv = 0.0f;
#pragma unroll
        for (int jj = 0; jj < 8; jj++) {
            float4 hv = *(const float4*)&Hrow[wv][j0 + 4 * jj];
            accv += hv.x * w2c[4 * jj + 0] + hv.y * w2c[4 * jj + 1]
                  + hv.z * w2c[4 * jj + 2] + hv.w * w2c[4 * jj + 3];
        }
        accv += __shfl_xor(accv, 32);   // combine half-partials (width 64)
        float v = fmaxf(fmaf(acn.x, accv, b2k), 0.0f);
        int gb = batch[n];               // wave-uniform scalar load
        if (gb != curg) {
            if (curg >= 0 && jh == 0)
                atomicAdd(&gsumi[curg * 32 + k], __float2int_rn(racc * POOL_SCALE));
            racc = 0.0f; curg = gb;
        }
        racc += v;
    }
    if (curg >= 0 && jh == 0)
        atomicAdd(&gsumi[curg * 32 + k], __float2int_rn(racc * POOL_SCALE));
}

// ---- readout (absorbs the batch binary search) ----
__global__ void k_readout(const int* __restrict__ gsumi, const int* __restrict__ batch,
                          const float* __restrict__ Wfc, const float* __restrict__ bfc,
                          float* __restrict__ out) {
    __shared__ int lb[N_GRAPHS + 1];
    int b = threadIdx.x;
    if (b <= N_GRAPHS) {
        int lo = 0, hi = N_NODES;
        while (lo < hi) {
            int mid = (lo + hi) >> 1;
            if (batch[mid] < b) lo = mid + 1; else hi = mid;
        }
        lb[b] = lo;
    }
    __syncthreads();
    if (b < N_GRAPHS) {
        float inv = 1.0f / fmaxf((float)(lb[b + 1] - lb[b]), 1.0f);
        float acc = bfc[0];
#pragma unroll
        for (int k = 0; k < 32; k++)
            acc += (float)gsumi[b * 32 + k] * POOL_INV * inv * Wfc[k];
        out[b] = 1.0f / (1.0f + expf(-acc));
    }
}

// ---- launch ----
extern "C" void kernel_launch(void* const* d_in, const int* in_sizes, int n_in,
                              void* d_out, int out_size, void* d_ws, size_t ws_size,
                              hipStream_t stream) {
    const float* x    = (const float*)d_in[0];
    const int*   ei   = (const int*)d_in[1];
    const int*   batch= (const int*)d_in[2];
    const float* W1   = (const float*)d_in[3];
    const float* b1   = (const float*)d_in[4];
    const float* W2   = (const float*)d_in[5];
    const float* b2   = (const float*)d_in[6];
    const float* Wfc  = (const float*)d_in[7];
    const float* bfc  = (const float*)d_in[8];
    float* out = (float*)d_out;

    const int* srcIdx = ei;
    const int* dstIdx = ei + N_EDGES;

    char* w = (char*)d_ws;
    unsigned int* gcur    = (unsigned int*)w; w += ((NBUCK + 64) & ~63) * 4;
    unsigned int* packed  = (unsigned int*)w; w += (size_t)NBUCK * CAP_E * 4;   // padded bucket regions
    unsigned int* packed2 = (unsigned int*)w; w += (size_t)(N_EDGES + 64) * 4;  // contiguous
    unsigned int* rowstart= (unsigned int*)w; w += (size_t)(NBUCK * BW + 64) * 4;
    float* dinv = (float*)w;                  w += (size_t)N_NODES * 4;
    float* sbuf = (float*)w;                  w += (size_t)N_NODES * 4;
    float2* ac  = (float2*)w;                 w += (size_t)(N_NODES + 8) * 8;
    int* gsumi  = (int*)w;                    w += (size_t)N_GRAPHS * 32 * 4;

    hipMemsetAsync(gcur, 0, (size_t)NBUCK * 4, stream);
    hipMemsetAsync(gsumi, 0, (size_t)N_GRAPHS * 32 * 4, stream);

    void* bargs[] = { (void*)&srcIdx, (void*)&dstIdx, (void*)&gcur, (void*)&packed,
                      (void*)&packed2, (void*)&rowstart, (void*)&x, (void*)&dinv,
                      (void*)&sbuf, (void*)&ac };
    hipLaunchCooperativeKernel((const void*)k_build, dim3(NBUCK), dim3(1024), bargs, 0, stream);

    k_l2<<<(N_NODES + 4 * NPW - 1) / (4 * NPW), 256, 0, stream>>>(rowstart, packed2, ac, W1, b1, W2, b2, batch, gsumi);
    k_readout<<<1, 128, 0, stream>>>(gsumi, batch, Wfc, bfc, out);
}

// Round 16
// 208.606 us; speedup vs baseline: 1.3880x; 1.3880x over previous
//
#include <hip/hip_runtime.h>
#include <math.h>

#define N_NODES 100000
#define N_EDGES 3200000
#define N_GRAPHS 64
#define BW 512                               // nodes per bucket
#define LSH 9
#define LMASK 511u
#define NBUCK ((N_NODES + BW - 1) / BW)      // 196
#define CHUNK_E 16384
#define NCHUNK ((N_EDGES + CHUNK_E - 1) / CHUNK_E)  // 196
#define CAP_E 18432                          // per-bucket capacity in padded 'packed' (mean 16327, +16 sigma)
#define POOL_SCALE 1024.0f
#define POOL_INV (1.0f / 1024.0f)
#define SENT ((unsigned int)N_NODES << LSH)  // sentinel edge -> ac[N_NODES] == (0,0)

// ---- pass D (self-reserving): per-chunk LDS hist over dst -> one global
// fetch_add per nonzero bucket -> scatter into the bucket's FIXED-CAPACITY
// region [b*CAP_E ...). After this kernel gcur[b] == exact bucket size.
// Bucket-confined writes keep the active write set at ~196 moving pointers —
// rounds 2/10: per-NODE cursors / random global atomics thrash the coherence
// point (100-200MB WRITE). Don't de-bucket. r15 post-mortem: cooperative
// grid.sync fusion of D/E1/E2 also regressed (1 blk/CU occupancy cap, 88MB
// WRITE from all-resident write sets, coop-launch graph overhead) — keep the
// three sequential launches.
__global__ void k_part(const int* __restrict__ src, const int* __restrict__ dst,
                       unsigned int* __restrict__ gcur, unsigned int* __restrict__ packed) {
    __shared__ unsigned int hist[NBUCK];
    __shared__ unsigned int sstart[NBUCK];
    for (int i = threadIdx.x; i < NBUCK; i += blockDim.x) hist[i] = 0u;
    __syncthreads();
    int e0 = blockIdx.x * CHUNK_E;
    int e1 = min(e0 + CHUNK_E, N_EDGES);
    for (int e = e0 + threadIdx.x; e < e1; e += blockDim.x)
        atomicAdd(&hist[dst[e] >> LSH], 1u);
    __syncthreads();
    for (int i = threadIdx.x; i < NBUCK; i += blockDim.x) {
        unsigned int h = hist[i];
        sstart[i] = h ? ((unsigned int)i * CAP_E + atomicAdd(&gcur[i], h)) : 0u;
        hist[i] = 0u;                        // reuse as scatter cursor
    }
    __syncthreads();
    for (int e = e0 + threadIdx.x; e < e1; e += blockDim.x) {
        int d = dst[e];
        int bk = d >> LSH;
        unsigned int pos = sstart[bk] + atomicAdd(&hist[bk], 1u);
        packed[pos] = ((unsigned int)src[e] << LSH) | ((unsigned int)d & LMASK);
    }
}

// ---- pass E1: per-bucket histogram + scan -> rowstart, dinv, s ----
// Absorbs the base scan — each block redundantly scans the 196 bucket sizes in
// LDS and takes its own exclusive prefix as the contiguous write base.
// hist[t] IS node (b*BW+t)'s degree — dinv/s computed here.
__global__ void k_sorta(const unsigned int* __restrict__ gcur,
                        const unsigned int* __restrict__ packed,
                        unsigned int* __restrict__ rowstart, const float* __restrict__ x,
                        float* __restrict__ dinv, float* __restrict__ s, float2* __restrict__ ac) {
    __shared__ unsigned int hist[BW];
    __shared__ unsigned int scan[BW];
    __shared__ unsigned int sdp[256];
    __shared__ unsigned int swbase;
    int b = blockIdx.x;
    int t = threadIdx.x;
    // phase 0: redundant scan of gcur[0..NBUCK) -> this bucket's exclusive base
    unsigned int gv = 0u;
    if (t < 256) { gv = (t < NBUCK) ? gcur[t] : 0u; sdp[t] = gv; }
    if (t < BW) hist[t] = 0u;
    if (b == 0 && t == 0) ac[N_NODES] = make_float2(0.0f, 0.0f);  // k_l2 sentinel
    __syncthreads();
    for (int o = 1; o < 256; o <<= 1) {
        unsigned int v = 0u;
        if (t < 256 && t >= o) v = sdp[t - o];
        __syncthreads();
        if (t < 256 && t >= o) sdp[t] += v;
        __syncthreads();
    }
    if (t == b) swbase = sdp[t] - gv;
    __syncthreads();
    unsigned int wbase = swbase;
    unsigned int r0 = (unsigned int)b * CAP_E;
    unsigned int r1 = r0 + gcur[b];
    for (unsigned int e = r0 + t; e < r1; e += blockDim.x)
        atomicAdd(&hist[packed[e] & LMASK], 1u);
    __syncthreads();
    if (t < BW) scan[t] = hist[t];
    __syncthreads();
    for (int o = 1; o < BW; o <<= 1) {
        unsigned int v = 0u;
        if (t < BW && t >= o) v = scan[t - o];
        __syncthreads();
        if (t < BW && t >= o) scan[t] += v;
        __syncthreads();
    }
    if (t < BW) {
        unsigned int deg = hist[t];
        rowstart[b * BW + t] = wbase + scan[t] - deg;
        int n = b * BW + t;
        if (n < N_NODES) {
            float di = 1.0f / sqrtf((float)(deg + 1u));  // +1 self-loop
            dinv[n] = di;
            s[n] = x[n] * di;
        }
    }
}

// ---- pass E2: scatter padded packed -> contiguous packed2, FUSED with layer 1 ----
// ABSOLUTE cursors from rowstart (no base dependency). Per edge,
// fsum[d] += s[src] (native ds_add_f32). Accumulation order is
// LDS-atomic-nondeterministic: same class as the edge order (already atomic);
// the int-quantized pooling absorbs it.
__global__ void k_sortb(const unsigned int* __restrict__ gcur,
                        const unsigned int* __restrict__ packed,
                        const unsigned int* __restrict__ rowstart,
                        unsigned int* __restrict__ packed2,
                        const float* __restrict__ dinv, const float* __restrict__ s,
                        float2* __restrict__ ac) {
    __shared__ unsigned int cur[BW];
    __shared__ float fsum[BW];
    int b = blockIdx.x;
    unsigned int r0 = (unsigned int)b * CAP_E;
    unsigned int r1 = r0 + gcur[b];
    if (threadIdx.x < BW) {
        cur[threadIdx.x] = rowstart[b * BW + threadIdx.x];   // absolute position
        fsum[threadIdx.x] = 0.0f;
    }
    __syncthreads();
    for (unsigned int e = r0 + threadIdx.x; e < r1; e += blockDim.x) {
        unsigned int p = packed[e];
        unsigned int d = p & LMASK;
        unsigned int pos = atomicAdd(&cur[d], 1u);
        packed2[pos] = p;
        atomicAdd(&fsum[d], s[p >> LSH]);   // layer-1 neighbor sum (ds_add_f32, L2-resident gather)
    }
    __syncthreads();
    if (threadIdx.x < BW) {
        int n = b * BW + threadIdx.x;
        if (n < N_NODES) {
            float di = dinv[n];
            ac[n] = make_float2(di, di * di * (fsum[threadIdx.x] + s[n]));
        }
    }
}

// ---- layer 2: one 64-lane wave per node, lane j = column j ----
// ROUND-5 KERNEL VERBATIM — proven 36 VGPR, zero scratch, 53-56 µs, FETCH 10 MB.
// DO NOT EDIT THIS KERNEL'S BODY: rounds 6/7/8 each made small changes (packed
// math; prefetch+4 accumulators; even a 2-accumulator algebra tweak) and ALL
// tipped the register allocator into demoting w2c[32] to scratch — 100-310 MB
// of HBM scratch traffic, 2-3x kernel slowdown, and graph-replay-wide damage.
// The codegen sits exactly on a register-bucket boundary.
#define NPW 8

#define EDGE_PAIR(P) { \
    float4 q_ = Epair4[(P)]; \
    H += fmaxf(fmaf(q_.y, w1j, q_.x * b1j), 0.0f); \
    H += fmaxf(fmaf(q_.w, w1j, q_.z * b1j), 0.0f); }

#define BLOCK16(P0) { \
    EDGE_PAIR((P0) + 0) EDGE_PAIR((P0) + 1) EDGE_PAIR((P0) + 2) EDGE_PAIR((P0) + 3) \
    EDGE_PAIR((P0) + 4) EDGE_PAIR((P0) + 5) EDGE_PAIR((P0) + 6) EDGE_PAIR((P0) + 7) }

__global__ __launch_bounds__(256, 6)
void k_l2(const unsigned int* __restrict__ rowstart, const unsigned int* __restrict__ packed2,
          const float2* __restrict__ ac,
          const float* __restrict__ W1, const float* __restrict__ b1,
          const float* __restrict__ W2, const float* __restrict__ b2,
          const int* __restrict__ batch, int* __restrict__ gsumi) {
    __shared__ float Hrow[4][64];    // one 64-float row per wave; wave-private
    __shared__ float4 Ebuf[4][32];   // 64 (ax,ay) pairs per wave, read as float4 (2 edges/read)
    const int lane = threadIdx.x & 63;
    const int wv   = threadIdx.x >> 6;
    const int k    = lane & 31;     // output column for matvec/pool
    const int jh   = lane >> 5;     // which half of the 64-wide hidden dim this lane reduces
    const int j0   = jh * 32;

    const float w1j = W1[lane];
    const float b1j = b1[lane];
    const float b2k = b2[k];
    float w2c[32];
#pragma unroll
    for (int j = 0; j < 32; j++) w2c[j] = W2[(j0 + j) * 32 + k];

    float4* Epair4 = &Ebuf[wv][0];                 // wave-uniform base
    float2* Ewr    = (float2*)&Ebuf[wv][0];        // per-lane write slot

    int n0 = (blockIdx.x * 4 + wv) * NPW;
    float racc = 0.0f;
    int curg = -1;
    for (int i = 0; i < NPW; i++) {
        int n = n0 + i;
        if (n >= N_NODES) break;
        unsigned int rs = rowstart[n], re = rowstart[n + 1];
        float2 acn = ac[n];
        // self-loop contribution
        float H = fmaxf(fmaf(acn.y, w1j, acn.x * b1j), 0.0f);
        unsigned int e0 = rs;
        // full 64-slot batches (deg >= 64, rare at Poisson(32))
        while (e0 + 64u <= re) {
            unsigned int p = packed2[e0 + lane];     // all lanes valid
            Ewr[lane] = ac[p >> LSH];                // gather -> wave-private LDS (ds_write_b64)
            BLOCK16(0) BLOCK16(8) BLOCK16(16) BLOCK16(24)
            e0 += 64u;
        }
        unsigned int rem = re - e0;                  // 0..63
        if (rem) {
            unsigned int idx = e0 + lane;
            unsigned int p = SENT;                   // sentinel -> ac[N_NODES] == (0,0)
            if (idx < re) p = packed2[idx];          // exec-masked load, no OOB
            Ewr[lane] = ac[p >> LSH];
            switch ((rem + 15u) >> 4) {              // 1..4 blocks of 16 slots (8 pairs)
                case 4: BLOCK16(24); [[fallthrough]];
                case 3: BLOCK16(16); [[fallthrough]];
                case 2: BLOCK16(8);  [[fallthrough]];
                case 1: BLOCK16(0);
            }
        }
        // matvec: out_k = relu(dinv_n * (H . W2[:,k]) + b2[k])
        Hrow[wv][lane] = H;     // same-wave ds ordering: visible to this wave without barrier
        float accv = 0.0f;
#pragma unroll
        for (int jj = 0; jj < 8; jj++) {
            float4 hv = *(const float4*)&Hrow[wv][j0 + 4 * jj];
            accv += hv.x * w2c[4 * jj + 0] + hv.y * w2c[4 * jj + 1]
                  + hv.z * w2c[4 * jj + 2] + hv.w * w2c[4 * jj + 3];
        }
        accv += __shfl_xor(accv, 32);   // combine half-partials (width 64)
        float v = fmaxf(fmaf(acn.x, accv, b2k), 0.0f);
        int gb = batch[n];               // wave-uniform scalar load
        if (gb != curg) {
            if (curg >= 0 && jh == 0)
                atomicAdd(&gsumi[curg * 32 + k], __float2int_rn(racc * POOL_SCALE));
            racc = 0.0f; curg = gb;
        }
        racc += v;
    }
    if (curg >= 0 && jh == 0)
        atomicAdd(&gsumi[curg * 32 + k], __float2int_rn(racc * POOL_SCALE));
}

// ---- readout (absorbs the batch binary search) ----
__global__ void k_readout(const int* __restrict__ gsumi, const int* __restrict__ batch,
                          const float* __restrict__ Wfc, const float* __restrict__ bfc,
                          float* __restrict__ out) {
    __shared__ int lb[N_GRAPHS + 1];
    int b = threadIdx.x;
    if (b <= N_GRAPHS) {
        int lo = 0, hi = N_NODES;
        while (lo < hi) {
            int mid = (lo + hi) >> 1;
            if (batch[mid] < b) lo = mid + 1; else hi = mid;
        }
        lb[b] = lo;
    }
    __syncthreads();
    if (b < N_GRAPHS) {
        float inv = 1.0f / fmaxf((float)(lb[b + 1] - lb[b]), 1.0f);
        float acc = bfc[0];
#pragma unroll
        for (int k = 0; k < 32; k++)
            acc += (float)gsumi[b * 32 + k] * POOL_INV * inv * Wfc[k];
        out[b] = 1.0f / (1.0f + expf(-acc));
    }
}

// ---- launch ----
extern "C" void kernel_launch(void* const* d_in, const int* in_sizes, int n_in,
                              void* d_out, int out_size, void* d_ws, size_t ws_size,
                              hipStream_t stream) {
    const float* x    = (const float*)d_in[0];
    const int*   ei   = (const int*)d_in[1];
    const int*   batch= (const int*)d_in[2];
    const float* W1   = (const float*)d_in[3];
    const float* b1   = (const float*)d_in[4];
    const float* W2   = (const float*)d_in[5];
    const float* b2   = (const float*)d_in[6];
    const float* Wfc  = (const float*)d_in[7];
    const float* bfc  = (const float*)d_in[8];
    float* out = (float*)d_out;

    const int* srcIdx = ei;
    const int* dstIdx = ei + N_EDGES;

    char* w = (char*)d_ws;
    unsigned int* gcur    = (unsigned int*)w; w += ((NBUCK + 64) & ~63) * 4;
    unsigned int* packed  = (unsigned int*)w; w += (size_t)NBUCK * CAP_E * 4;   // padded bucket regions
    unsigned int* packed2 = (unsigned int*)w; w += (size_t)(N_EDGES + 64) * 4;  // contiguous
    unsigned int* rowstart= (unsigned int*)w; w += (size_t)(NBUCK * BW + 64) * 4;
    float* dinv = (float*)w;                  w += (size_t)N_NODES * 4;
    float* sbuf = (float*)w;                  w += (size_t)N_NODES * 4;
    float2* ac  = (float2*)w;                 w += (size_t)(N_NODES + 8) * 8;
    int* gsumi  = (int*)w;                    w += (size_t)N_GRAPHS * 32 * 4;

    hipMemsetAsync(gcur, 0, (size_t)NBUCK * 4, stream);
    hipMemsetAsync(gsumi, 0, (size_t)N_GRAPHS * 32 * 4, stream);

    k_part <<<NCHUNK, 1024, 0, stream>>>(srcIdx, dstIdx, gcur, packed);
    k_sorta<<<NBUCK, 1024, 0, stream>>>(gcur, packed, rowstart, x, dinv, sbuf, ac);
    k_sortb<<<NBUCK, 1024, 0, stream>>>(gcur, packed, rowstart, packed2, dinv, sbuf, ac);
    k_l2   <<<(N_NODES + 4 * NPW - 1) / (4 * NPW), 256, 0, stream>>>(rowstart, packed2, ac, W1, b1, W2, b2, batch, gsumi);
    k_readout<<<1, 128, 0, stream>>>(gsumi, batch, Wfc, bfc, out);
}